// Round 1
// baseline (101.557 us; speedup 1.0000x reference)
//
#include <hip/hip_runtime.h>

// Lorenz Taylor-step map: pure elementwise over 4194304 (y0,y1,y2) fp32 triples.
// Memory-bound: 12B in + 12B out per triple. Each thread processes 4 triples
// = 3 float4 loads + 3 float4 stores (fully-consumed cache lines per wave).

__device__ __forceinline__ void lorenz_elem(float yi0, float yi1, float yi2,
                                            float& o0, float& o1, float& o2) {
    const float h  = 0.01f;
    const float h2 = h * h;     // 1e-4
    const float h3 = h2 * h;    // 1e-6
    const float a0 = 0.5f;
    const float a1 = 1.0f / 6.0f;
    const float a2 = 1.0f / 6.0f;
    const float a4 = 3.0f / 24.0f;
    const float a5 = 1.0f / 24.0f;
    const float a6 = 1.0f / 24.0f;
    const float beta = 8.0f / 3.0f;

    const float y0 = 10.0f * yi0;
    const float y1 = 10.0f * yi1;
    const float y2 = 10.0f * yi2;

    // f(y)
    const float f0 = 10.0f * y1 - 10.0f * y0;
    const float f1 = 28.0f * y0 - y0 * y2 - y1;
    const float f2 = y0 * y1 - beta * y2;

    // dff = J(y) * f
    const float dff0 = -10.0f * f0 + 10.0f * f1;
    const float dff1 = (28.0f - y2) * f0 - f1 - y0 * f2;
    const float dff2 = y1 * f0 + y0 * f1 - beta * f2;

    // dfdff = J * dff
    const float dfdff0 = -10.0f * dff0 + 10.0f * dff1;
    const float dfdff1 = (28.0f - y2) * dff0 - dff1 - y0 * dff2;
    const float dfdff2 = y1 * dff0 + y0 * dff1 - beta * dff2;

    // ddfff = ddf(f,f)
    const float ddfff0 = 0.0f;
    const float ddfff1 = -2.0f * f0 * f2;
    const float ddfff2 = 2.0f * f0 * f1;

    // ddfdfff = ddf(dff, f)
    const float ddfdfff0 = 0.0f;
    const float ddfdfff1 = -dff0 * f2 - dff2 * f0;
    const float ddfdfff2 = dff0 * f1 + dff1 * f0;

    // dfddfff = J * ddfff  (faithfully keeping reference's y0*f1 term in comp 2)
    const float dfddfff0 = -10.0f * ddfff0 + 10.0f * ddfff1;
    const float dfddfff1 = (28.0f - y2) * ddfff0 - ddfff1 - y0 * ddfff2;
    const float dfddfff2 = y1 * ddfff0 + y0 * f1 - beta * ddfff2;

    // dfdfdff = J * dfdff
    const float dfdfdff0 = -10.0f * dfdff0 + 10.0f * dfdff1;
    const float dfdfdff1 = (28.0f - y2) * dfdff0 - dfdff1 - y0 * dfdff2;
    const float dfdfdff2 = y1 * dfdff0 + y0 * dfdff1 - beta * dfdff2;

    const float c0 = f0 + a0 * h * dff0 + a1 * h2 * ddfff0 + a2 * h2 * dfdff0
                   + a4 * h3 * ddfdfff0 + a5 * h3 * dfddfff0 + a6 * h3 * dfdfdff0;
    const float c1 = f1 + a0 * h * dff1 + a1 * h2 * ddfff1 + a2 * h2 * dfdff1
                   + a4 * h3 * ddfdfff1 + a5 * h3 * dfddfff1 + a6 * h3 * dfdfdff1;
    const float c2 = f2 + a0 * h * dff2 + a1 * h2 * ddfff2 + a2 * h2 * dfdff2
                   + a4 * h3 * ddfdfff2 + a5 * h3 * dfddfff2 + a6 * h3 * dfdfdff2;

    o0 = c0 * 0.1f;
    o1 = c1 * 0.1f;
    o2 = c2 * 0.1f;
}

// Each thread: 4 triples = 12 floats = 3 float4 loads/stores at float4-index 3t..3t+2.
__global__ void __launch_bounds__(256)
lorenz_kernel(const float4* __restrict__ in, float4* __restrict__ out, int n_vec4_triples) {
    const int t = blockIdx.x * blockDim.x + threadIdx.x;
    if (t >= n_vec4_triples) return;

    const float4 v0 = in[3 * t + 0];
    const float4 v1 = in[3 * t + 1];
    const float4 v2 = in[3 * t + 2];

    // element 0: (v0.x, v0.y, v0.z)   element 1: (v0.w, v1.x, v1.y)
    // element 2: (v1.z, v1.w, v2.x)   element 3: (v2.y, v2.z, v2.w)
    float4 r0, r1, r2;
    lorenz_elem(v0.x, v0.y, v0.z, r0.x, r0.y, r0.z);
    lorenz_elem(v0.w, v1.x, v1.y, r0.w, r1.x, r1.y);
    lorenz_elem(v1.z, v1.w, v2.x, r1.z, r1.w, r2.x);
    lorenz_elem(v2.y, v2.z, v2.w, r2.y, r2.z, r2.w);

    out[3 * t + 0] = r0;
    out[3 * t + 1] = r1;
    out[3 * t + 2] = r2;
}

extern "C" void kernel_launch(void* const* d_in, const int* in_sizes, int n_in,
                              void* d_out, int out_size, void* d_ws, size_t ws_size,
                              hipStream_t stream) {
    const float* y = (const float*)d_in[0];
    float* out = (float*)d_out;

    const int n_floats = in_sizes[0];          // 4194304 * 3 = 12582912
    const int n_threads = n_floats / 12;       // 4 triples (12 floats) per thread
    const int block = 256;
    const int grid = (n_threads + block - 1) / block;

    lorenz_kernel<<<grid, block, 0, stream>>>((const float4*)y, (float4*)out, n_threads);
}

// Round 2
// 98.978 us; speedup vs baseline: 1.0261x; 1.0261x over previous
//
#include <hip/hip_runtime.h>

// Lorenz Taylor-step map: pure elementwise over 4194304 (y0,y1,y2) fp32 triples.
// Memory-bound: 12B in + 12B out per triple (~100 MB total, roofline ~16us).
// Round 2: LDS-staged AoS handling. All global loads/stores are perfectly
// contiguous per wave (64 x 16B = 1KiB per instruction); the 48B-stride
// triple gather happens in LDS, where stride-48 ds_read_b128 is conflict-free
// (8 consecutive lanes cover all 32 banks exactly once).

__device__ __forceinline__ void lorenz_elem(float yi0, float yi1, float yi2,
                                            float& o0, float& o1, float& o2) {
    const float h  = 0.01f;
    const float h2 = h * h;     // 1e-4
    const float h3 = h2 * h;    // 1e-6
    const float a0 = 0.5f;
    const float a1 = 1.0f / 6.0f;
    const float a2 = 1.0f / 6.0f;
    const float a4 = 3.0f / 24.0f;
    const float a5 = 1.0f / 24.0f;
    const float a6 = 1.0f / 24.0f;
    const float beta = 8.0f / 3.0f;

    const float y0 = 10.0f * yi0;
    const float y1 = 10.0f * yi1;
    const float y2 = 10.0f * yi2;

    // f(y)
    const float f0 = 10.0f * y1 - 10.0f * y0;
    const float f1 = 28.0f * y0 - y0 * y2 - y1;
    const float f2 = y0 * y1 - beta * y2;

    // dff = J(y) * f
    const float dff0 = -10.0f * f0 + 10.0f * f1;
    const float dff1 = (28.0f - y2) * f0 - f1 - y0 * f2;
    const float dff2 = y1 * f0 + y0 * f1 - beta * f2;

    // dfdff = J * dff
    const float dfdff0 = -10.0f * dff0 + 10.0f * dff1;
    const float dfdff1 = (28.0f - y2) * dff0 - dff1 - y0 * dff2;
    const float dfdff2 = y1 * dff0 + y0 * dff1 - beta * dff2;

    // ddfff = ddf(f,f)
    const float ddfff0 = 0.0f;
    const float ddfff1 = -2.0f * f0 * f2;
    const float ddfff2 = 2.0f * f0 * f1;

    // ddfdfff = ddf(dff, f)
    const float ddfdfff0 = 0.0f;
    const float ddfdfff1 = -dff0 * f2 - dff2 * f0;
    const float ddfdfff2 = dff0 * f1 + dff1 * f0;

    // dfddfff = J * ddfff  (faithfully keeping reference's y0*f1 term in comp 2)
    const float dfddfff0 = -10.0f * ddfff0 + 10.0f * ddfff1;
    const float dfddfff1 = (28.0f - y2) * ddfff0 - ddfff1 - y0 * ddfff2;
    const float dfddfff2 = y1 * ddfff0 + y0 * f1 - beta * ddfff2;

    // dfdfdff = J * dfdff
    const float dfdfdff0 = -10.0f * dfdff0 + 10.0f * dfdff1;
    const float dfdfdff1 = (28.0f - y2) * dfdff0 - dfdff1 - y0 * dfdff2;
    const float dfdfdff2 = y1 * dfdff0 + y0 * dfdff1 - beta * dfdff2;

    const float c0 = f0 + a0 * h * dff0 + a1 * h2 * ddfff0 + a2 * h2 * dfdff0
                   + a4 * h3 * ddfdfff0 + a5 * h3 * dfddfff0 + a6 * h3 * dfdfdff0;
    const float c1 = f1 + a0 * h * dff1 + a1 * h2 * ddfff1 + a2 * h2 * dfdff1
                   + a4 * h3 * ddfdfff1 + a5 * h3 * dfddfff1 + a6 * h3 * dfdfdff1;
    const float c2 = f2 + a0 * h * dff2 + a1 * h2 * ddfff2 + a2 * h2 * dfdff2
                   + a4 * h3 * ddfdfff2 + a5 * h3 * dfddfff2 + a6 * h3 * dfdfdff2;

    o0 = c0 * 0.1f;
    o1 = c1 * 0.1f;
    o2 = c2 * 0.1f;
}

// Block of 256 threads handles 768 contiguous float4s = 1024 triples.
// 12582912 floats = 3145728 float4s = 4096 blocks exactly (no tail).
__global__ void __launch_bounds__(256)
lorenz_kernel(const float4* __restrict__ in, float4* __restrict__ out, int n4) {
    __shared__ float4 lds[768];   // 12 KiB

    const int tid  = threadIdx.x;
    const int base = blockIdx.x * 768;

    // Stage in: 3 perfectly-contiguous wave loads (stride 16B across lanes).
    if (base + tid < n4)       lds[tid]       = in[base + tid];
    if (base + tid + 256 < n4) lds[tid + 256] = in[base + tid + 256];
    if (base + tid + 512 < n4) lds[tid + 512] = in[base + tid + 512];
    __syncthreads();

    // Gather this thread's 4 triples (stride-48B ds_read_b128: conflict-free).
    const float4 v0 = lds[3 * tid + 0];
    const float4 v1 = lds[3 * tid + 1];
    const float4 v2 = lds[3 * tid + 2];

    float4 r0, r1, r2;
    lorenz_elem(v0.x, v0.y, v0.z, r0.x, r0.y, r0.z);
    lorenz_elem(v0.w, v1.x, v1.y, r0.w, r1.x, r1.y);
    lorenz_elem(v1.z, v1.w, v2.x, r1.z, r1.w, r2.x);
    lorenz_elem(v2.y, v2.z, v2.w, r2.y, r2.z, r2.w);

    __syncthreads();   // all reads done before overwrite
    lds[3 * tid + 0] = r0;
    lds[3 * tid + 1] = r1;
    lds[3 * tid + 2] = r2;
    __syncthreads();

    // Stage out: 3 perfectly-contiguous wave stores.
    if (base + tid < n4)       out[base + tid]       = lds[tid];
    if (base + tid + 256 < n4) out[base + tid + 256] = lds[tid + 256];
    if (base + tid + 512 < n4) out[base + tid + 512] = lds[tid + 512];
}

extern "C" void kernel_launch(void* const* d_in, const int* in_sizes, int n_in,
                              void* d_out, int out_size, void* d_ws, size_t ws_size,
                              hipStream_t stream) {
    const float* y = (const float*)d_in[0];
    float* out = (float*)d_out;

    const int n_floats = in_sizes[0];          // 4194304 * 3 = 12582912
    const int n4 = n_floats / 4;               // 3145728 float4s
    const int block = 256;
    const int grid = (n4 + 3 * block - 1) / (3 * block);   // 768 float4s per block

    lorenz_kernel<<<grid, block, 0, stream>>>((const float4*)y, (float4*)out, n4);
}